// Round 16
// baseline (898.712 us; speedup 1.0000x reference)
//
#include <hip/hip_runtime.h>
#include <hip/hip_bf16.h>

typedef __attribute__((ext_vector_type(8))) short short8;
typedef __attribute__((ext_vector_type(4))) float f32x4;

#define NT 32
#define NB 64
#define NA 16
#define NF 128
#define DT 512
#define NH 8
#define NHD 64

// f32 -> bf16 RNE via compiler intrinsic (m240: compiler casts are fast AND correct;
// hand-written v_cvt_pk_bf16_f32 asm was r10's correctness bug)
__device__ __forceinline__ unsigned short f2b(float f) {
  return __bfloat16_as_ushort(__float2bfloat16(f));
}
__device__ __forceinline__ float b2f(unsigned short u) {
  union { unsigned u; float f; } c; c.u = ((unsigned)u) << 16;
  return c.f;
}
__device__ __forceinline__ unsigned cvt2(float a, float b) {
  return (unsigned)f2b(a) | ((unsigned)f2b(b) << 16);
}

__device__ __forceinline__ void gload16(const void* g, void* l) {
  __builtin_amdgcn_global_load_lds(
      (const __attribute__((address_space(1))) void*)g,
      (__attribute__((address_space(3))) void*)l, 16, 0, 0);
}

#define BAR() asm volatile("s_barrier" ::: "memory")

// ---------------- all 4 weight casts in one launch ----------------
__global__ __launch_bounds__(256) void cast4_kernel(const float* __restrict__ w0,
                                                    const float* __restrict__ w1,
                                                    const float* __restrict__ w2,
                                                    const float* __restrict__ w3,
                                                    unsigned short* __restrict__ dst) {
  const int mat = blockIdx.x >> 7;
  const float* src = (mat == 0) ? w0 : (mat == 1) ? w1 : (mat == 2) ? w2 : w3;
  long i = ((long)(blockIdx.x & 127) * 256 + threadIdx.x) * 8;
  float4 v0 = *(const float4*)(src + i);
  float4 v1 = *(const float4*)(src + i + 4);
  uint4 o;
  o.x = cvt2(v0.x, v0.y);
  o.y = cvt2(v0.z, v0.w);
  o.z = cvt2(v1.x, v1.y);
  o.w = cvt2(v1.z, v1.w);
  *(uint4*)(dst + (long)mat * 512 * 512 + i) = o;
}

// =============== 128x256 GEMM, f32 A staged in LDS; B frags DIRECT FROM L2 ===============
// r13 skeleton (proven best), minus the whole B LDS path: B is the 0.5 MB L2-resident
// weight panel, so B frags are 8x global dwordx4 per tile per wave (hidden under MFMA +
// cross-wave overlap). Removes 8/12 ds_reads, 4/8 stage gloads, all B bank conflicts;
// LDS 64->32 KB. 256 threads = 4 waves (2M x 2N), per-wave 64x128 (acc 4x8), BK=32,
// 16 K-tiles, 2 A slots. Stage = 4 A gloads -> counted vmcnt(4); B reg-loads issued
// AFTER the vmcnt asm (memory-clobber ordered; older-unknown-loads => compiler waits
// for B remain safe). A swizzle unchanged: 16B-chunk ^= (row&7), involution.
// MODE 0 = KV (NCB=2: colTiles 0,1 -> K row-linear; 2,3 -> V row-permuted)
// MODE 1 = Q  (NCB=1: bf16 row-linear)
template <int MODE, int NCB>
__global__ __launch_bounds__(256, 2) void gemm_f32a(const float* __restrict__ A,
                                                    const unsigned short* __restrict__ Bg,
                                                    const float* __restrict__ bias0,
                                                    const float* __restrict__ bias1,
                                                    unsigned short* __restrict__ C0,
                                                    unsigned short* __restrict__ C1) {
  __shared__ __align__(16) float Asf[2][128 * 32];  // 16 KB / slot, 2 slots
  const int tid = threadIdx.x;
  const int lane = tid & 63;
  const int l4 = lane & 15, lg = lane >> 4;
  const int w = tid >> 6;
  const int wm = w >> 1, wn = w & 1;

  const int nwg = gridDim.x;
  const int bid = blockIdx.x;
  const int swz = (bid & 7) * (nwg >> 3) + (bid >> 3);
  const long rowTile = swz >> NCB;
  const int colTile = swz & ((1 << NCB) - 1);

  // A staging: wave w covers rows w*32 + j*8 + (lane>>3) (j=0..3), chunk lane&7,
  // source pre-swizzled ^ ((lane>>3)&7) (involution; j*8 ≡ 0 mod 8)
  const int sA = (lane & 7) ^ ((lane >> 3) & 7);
  const float* AglB = A + (rowTile * 128 + w * 32 + (lane >> 3)) * 512L + sA * 4;

  // B frag offsets (32-bit, base Bg in SGPRs): row = colTile*256 + wn*128 + n*16 + l4
  unsigned boff[8];
#pragma unroll
  for (int n = 0; n < 8; n++)
    boff[n] = (unsigned)((colTile * 256 + wn * 128 + n * 16 + l4) * 512 + lg * 8);

  auto stage = [&](int s, int kc) {
#pragma unroll
    for (int j = 0; j < 4; j++)
      gload16(AglB + j * (8 * 512L) + kc, &Asf[s][w * 1024 + j * 256]);
  };

  const f32x4 zero = {0.f, 0.f, 0.f, 0.f};
  f32x4 acc[4][8];
#pragma unroll
  for (int i = 0; i < 4; i++)
#pragma unroll
    for (int j = 0; j < 8; j++) acc[i][j] = zero;

  const int chA = (l4 & 7);

  stage(0, 0);

#pragma unroll 1
  for (int T = 0; T < 16; T++) {
    const int s = T & 1;
    BAR();  // all waves done reading slot s^1
    if (T < 15) {
      stage(s ^ 1, (T + 1) * 32);
      asm volatile("s_waitcnt vmcnt(4)" ::: "memory");  // tile T's 4 A-loads done
    } else {
      asm volatile("s_waitcnt vmcnt(0)" ::: "memory");
    }
    BAR();  // tile T's A resident for all waves
    // B frags straight from global (L2-resident weights)
    short8 bf[8];
#pragma unroll
    for (int n = 0; n < 8; n++)
      bf[n] = *(const short8*)(Bg + boff[n] + T * 32);
    // A frags from LDS (f32 -> bf16 pack)
    short8 af[4];
#pragma unroll
    for (int m = 0; m < 4; m++) {
      int ra = wm * 64 + m * 16 + l4;
      int c0 = (lg * 2) ^ chA;
      f32x4 p0 = *(const f32x4*)&Asf[s][ra * 32 + c0 * 4];
      f32x4 p1 = *(const f32x4*)&Asf[s][ra * 32 + (c0 ^ 1) * 4];
      union { unsigned u[4]; short8 s8; } cv;
      cv.u[0] = cvt2(p0[0], p0[1]);
      cv.u[1] = cvt2(p0[2], p0[3]);
      cv.u[2] = cvt2(p1[0], p1[1]);
      cv.u[3] = cvt2(p1[2], p1[3]);
      af[m] = cv.s8;
    }
    __builtin_amdgcn_s_setprio(1);
#pragma unroll
    for (int m = 0; m < 4; m++)
#pragma unroll
      for (int n = 0; n < 8; n++)
        acc[m][n] = __builtin_amdgcn_mfma_f32_16x16x32_bf16(af[m], bf[n], acc[m][n], 0, 0, 0);
    __builtin_amdgcn_s_setprio(0);
  }

  const long rowBase = rowTile * 128 + wm * 64;

  if constexpr (MODE == 0) {  // KV
    if (colTile < 2) {        // K: row-linear ((t,f,b) reshape is a memory no-op)
#pragma unroll
      for (int n = 0; n < 8; n++) {
        int gCol = colTile * 256 + wn * 128 + n * 16 + l4;
        float bs = bias0[gCol];
#pragma unroll
        for (int m = 0; m < 4; m++)
#pragma unroll
          for (int r = 0; r < 4; r++) {
            long gRow = rowBase + m * 16 + lg * 4 + r;
            C0[gRow * 512 + gCol] = f2b(acc[m][n][r] + bs);
          }
      }
    } else {  // V: row (fi*64+bi) -> (bi*128+fi) within each t
#pragma unroll
      for (int n = 0; n < 8; n++) {
        int gCol = (colTile - 2) * 256 + wn * 128 + n * 16 + l4;
        float bs = bias1[gCol];
#pragma unroll
        for (int m = 0; m < 4; m++)
#pragma unroll
          for (int r = 0; r < 4; r++) {
            long gRow = rowBase + m * 16 + lg * 4 + r;
            long rr = gRow & 8191;
            long vrow = (gRow - rr) + ((rr & 63) << 7) + (rr >> 6);
            C1[vrow * 512 + gCol] = f2b(acc[m][n][r] + bs);
          }
      }
    }
  } else {  // Q: bf16 row-linear
#pragma unroll
    for (int n = 0; n < 8; n++) {
      int gCol = colTile * 256 + wn * 128 + n * 16 + l4;
      float bs = bias0[gCol];
#pragma unroll
      for (int m = 0; m < 4; m++)
#pragma unroll
        for (int r = 0; r < 4; r++) {
          long gRow = rowBase + m * 16 + lg * 4 + r;
          C0[gRow * 512 + gCol] = f2b(acc[m][n][r] + bs);
        }
    }
  }
}

// ---------------- O projection (r7-proven): glds bf16 A/B, 128^2, f32 out ----------------
__global__ __launch_bounds__(256) void gemm_o(const unsigned short* __restrict__ A,
                                              const unsigned short* __restrict__ Bg,
                                              const float* __restrict__ bias0,
                                              float* __restrict__ C) {
  __shared__ __align__(16) unsigned short As[128 * 32];
  __shared__ __align__(16) unsigned short Bs[128 * 32];
  const int tid = threadIdx.x;
  const int lane = tid & 63;
  const int l4 = lane & 15, lg = lane >> 4;
  const int w = tid >> 6;
  const int wm = w >> 1, wn = w & 1;

  const int nwg = gridDim.x;
  const int bid = blockIdx.x;
  const int swz = (bid & 7) * (nwg >> 3) + (bid >> 3);
  const long rowTile = swz >> 2;
  const int colTile = swz & 3;

  const int srow = lane >> 2;
  const int scol = (lane & 3) * 8;
  const unsigned short* Ab = A + (rowTile * 128 + w * 16 + srow) * 512L + scol;
  const unsigned short* Ab2 = Ab + 64 * 512L;
  const unsigned short* Bb = Bg + ((long)colTile * 128 + w * 16 + srow) * 512L + scol;
  const unsigned short* Bb2 = Bb + 64 * 512L;
  unsigned short* lA = As + w * 512;
  unsigned short* lA2 = As + (w + 4) * 512;
  unsigned short* lB = Bs + w * 512;
  unsigned short* lB2 = Bs + (w + 4) * 512;

  const f32x4 zero = {0.f, 0.f, 0.f, 0.f};
  f32x4 acc[4][4];
#pragma unroll
  for (int i = 0; i < 4; i++)
#pragma unroll
    for (int j = 0; j < 4; j++) acc[i][j] = zero;

  for (int k0 = 0; k0 < 512; k0 += 32) {
    gload16(Ab + k0, lA);
    gload16(Ab2 + k0, lA2);
    gload16(Bb + k0, lB);
    gload16(Bb2 + k0, lB2);
    __syncthreads();
    short8 af[4], bfr[4];
#pragma unroll
    for (int i = 0; i < 4; i++)
      af[i] = *(const short8*)(As + (wm * 64 + i * 16 + l4) * 32 + lg * 8);
#pragma unroll
    for (int j = 0; j < 4; j++)
      bfr[j] = *(const short8*)(Bs + (wn * 64 + j * 16 + l4) * 32 + lg * 8);
#pragma unroll
    for (int i = 0; i < 4; i++)
#pragma unroll
      for (int j = 0; j < 4; j++)
        acc[i][j] = __builtin_amdgcn_mfma_f32_16x16x32_bf16(af[i], bfr[j], acc[i][j], 0, 0, 0);
    __syncthreads();
  }

  const long rowBase = rowTile * 128 + wm * 64;
#pragma unroll
  for (int j = 0; j < 4; j++) {
    int gCol = colTile * 128 + wn * 64 + j * 16 + l4;
    float bs = bias0[gCol];
#pragma unroll
    for (int i = 0; i < 4; i++)
#pragma unroll
      for (int r = 0; r < 4; r++) {
        long gRow = rowBase + i * 16 + lg * 4 + r;
        long tt = gRow >> 10;
        long bi = (gRow >> 4) & 63;
        long ai = gRow & 15;
        long orow = ((tt * 16 + ai) << 6) + bi;
        C[orow * 512 + gCol] = acc[i][j][r] + bs;
      }
  }
}

// ---------------- attention (r15-proven): slice-staged K and V, MFMA QK^T + PV ----------------
__global__ __launch_bounds__(256) void attn_kernel(const unsigned short* __restrict__ Kst,
                                                   const unsigned short* __restrict__ Vst,
                                                   const unsigned short* __restrict__ Qst,
                                                   const int* __restrict__ mask,
                                                   float* __restrict__ wout,
                                                   unsigned short* __restrict__ attn_out) {
  __shared__ __align__(16) unsigned short wt[4][16][136];  // per-wave W^T bf16 [a][f]
  __shared__ __align__(16) unsigned short Vl[4][2][2048];  // per-wave slice bufs, 2 x 4KB
  __shared__ int msh[NF];
  const int tid = threadIdx.x;
  const int lane = tid & 63;
  const int l4 = lane & 15, lg = lane >> 4;
  const int w = tid >> 6;
  const int tb = blockIdx.x;
  const int b = tb & 63;
  if (tid < NF) msh[tid] = mask[b * NF + tid];
  __syncthreads();

  const unsigned short* Kbase = Kst + (long)tb * NF * DT;
  const unsigned short* Vbase = Vst + (long)tb * NF * DT;
  const unsigned short* Qbase = Qst + (long)tb * NA * DT;
  const f32x4 zero = {0.f, 0.f, 0.f, 0.f};

  const int vsr = lane >> 3;
  const int vsc = lane & 7;

  for (int hh = 0; hh < 2; hh++) {
    const int h = w * 2 + hh;
    const int co = h * 64;

    auto stageS = [&](const unsigned short* base, int buf, int sl) {
#pragma unroll
      for (int i = 0; i < 4; i++) {
        const unsigned short* src =
            base + (long)(sl * 32 + i * 8 + vsr) * DT + co + ((vsc ^ i) * 8);
        gload16(src, &Vl[w][buf][i * 512]);
      }
    };

    short8 qf0 = *(const short8*)(Qbase + (long)l4 * DT + co + lg * 8);
    short8 qf1 = *(const short8*)(Qbase + (long)l4 * DT + co + 32 + lg * 8);
    stageS(Kbase, 0, 0);
    stageS(Kbase, 1, 1);

    f32x4 acc[8];
#pragma unroll
    for (int i = 0; i < 8; i++) acc[i] = zero;
#pragma unroll
    for (int mh = 0; mh < 4; mh++) {
      const int buf = mh & 1;
      asm volatile("s_waitcnt vmcnt(4)" ::: "memory");
#pragma unroll
      for (int mm = 0; mm < 2; mm++) {
        const int m0 = mh * 2 + mm;
        const int r = mm * 16 + l4;
        short8 kf0 = *(const short8*)&Vl[w][buf][r * 64 + ((lg ^ (r >> 3)) * 8)];
        short8 kf1 = *(const short8*)&Vl[w][buf][r * 64 + (((4 + lg) ^ (r >> 3)) * 8)];
        acc[m0] = __builtin_amdgcn_mfma_f32_16x16x32_bf16(kf0, qf0, acc[m0], 0, 0, 0);
        acc[m0] = __builtin_amdgcn_mfma_f32_16x16x32_bf16(kf1, qf1, acc[m0], 0, 0, 0);
      }
      asm volatile("s_waitcnt lgkmcnt(0)" ::: "memory");
      __builtin_amdgcn_sched_barrier(0);
      if (mh < 2) stageS(Kbase, buf, mh + 2);
      else stageS(Vbase, buf, mh - 2);
    }

    float lv[8][4];
    float mx = -3.0e38f;
#pragma unroll
    for (int m0 = 0; m0 < 8; m0++)
#pragma unroll
      for (int r = 0; r < 4; r++) {
        int f = m0 * 16 + lg * 4 + r;
        float v = acc[m0][r] * 0.125f;
        if (msh[f] == 0) v = -1.0e9f;
        lv[m0][r] = v;
        mx = fmaxf(mx, v);
      }
    mx = fmaxf(mx, __shfl_xor(mx, 16, 64));
    mx = fmaxf(mx, __shfl_xor(mx, 32, 64));
    float s = 0.f;
#pragma unroll
    for (int m0 = 0; m0 < 8; m0++)
#pragma unroll
      for (int r = 0; r < 4; r++) {
        float p = __expf(lv[m0][r] - mx);
        lv[m0][r] = p;
        s += p;
      }
    s += __shfl_xor(s, 16, 64);
    s += __shfl_xor(s, 32, 64);
    float inv = 1.0f / s;
    float* wrow = wout + ((long)tb * NH + h) * (NF * NA);
#pragma unroll
    for (int m0 = 0; m0 < 8; m0++)
#pragma unroll
      for (int r = 0; r < 4; r++) {
        int f = m0 * 16 + lg * 4 + r;
        float wv = lv[m0][r] * inv;
        wrow[f * 16 + l4] = wv;
        wt[w][l4][f] = f2b(wv);
      }
    asm volatile("s_waitcnt lgkmcnt(0)" ::: "memory");
    __builtin_amdgcn_sched_barrier(0);

    f32x4 pacc[4];
#pragma unroll
    for (int m0 = 0; m0 < 4; m0++) pacc[m0] = zero;
#pragma unroll 1
    for (int ks = 0; ks < 4; ks++) {
      const int buf = ks & 1;
      if (ks < 3)
        asm volatile("s_waitcnt vmcnt(4)" ::: "memory");
      else
        asm volatile("s_waitcnt vmcnt(0)" ::: "memory");
      short8 wf = *(const short8*)&wt[w][l4][ks * 32 + lg * 8];
#pragma unroll
      for (int m0 = 0; m0 < 4; m0++) {
        const int hdl = m0 * 16 + l4;
        const int ch = ((hdl >> 3) ^ lg) & 7;
        const int cb = ch * 8 + (hdl & 7);
        short8 vf;
#pragma unroll
        for (int j = 0; j < 8; j++)
          vf[j] = (short)Vl[w][buf][(lg * 8 + j) * 64 + cb];
        pacc[m0] = __builtin_amdgcn_mfma_f32_16x16x32_bf16(vf, wf, pacc[m0], 0, 0, 0);
      }
      if (ks < 2) {
        asm volatile("s_waitcnt lgkmcnt(0)" ::: "memory");
        __builtin_amdgcn_sched_barrier(0);
        stageS(Vbase, buf, ks + 2);
      }
    }
#pragma unroll
    for (int m0 = 0; m0 < 4; m0++)
#pragma unroll
      for (int r = 0; r < 4; r++)
        attn_out[((long)tb * NA + l4) * DT + co + m0 * 16 + lg * 4 + r] = f2b(pacc[m0][r]);
  }
}

extern "C" void kernel_launch(void* const* d_in, const int* in_sizes, int n_in,
                              void* d_out, int out_size, void* d_ws, size_t ws_size,
                              hipStream_t stream) {
  const float* q_embeds = (const float*)d_in[0];
  const float* ctx = (const float*)d_in[1];
  const int* mask = (const int*)d_in[2];
  const float* Wq = (const float*)d_in[3];
  const float* bq = (const float*)d_in[4];
  const float* Wk = (const float*)d_in[5];
  const float* bk = (const float*)d_in[6];
  const float* Wv = (const float*)d_in[7];
  const float* bv = (const float*)d_in[8];
  const float* Wo = (const float*)d_in[9];
  const float* bo = (const float*)d_in[10];

  float* out0 = (float*)d_out;                   // (t,a,b,d) f32
  float* wout = out0 + (long)NT * NA * NB * DT;  // (t,b,H,f,a) f32

  const long W_ELEMS = 4L * 512 * 512;
  const long MQ = (long)NT * NB * NA;    // 32768
  const long MKV = (long)NT * NF * NB;   // 262144
  unsigned short* Wb = (unsigned short*)d_ws;
  unsigned short* Qst = Wb + W_ELEMS;
  unsigned short* Kst = Qst + MQ * DT;
  unsigned short* Vst = Kst + MKV * DT;
  unsigned short* attnst = Vst + MKV * DT;
  size_t needed = (size_t)(W_ELEMS + 2 * MQ * DT + 2 * MKV * DT) * 2;
  if (ws_size < needed) return;

  cast4_kernel<<<512, 256, 0, stream>>>(Wq, Wk, Wv, Wo, Wb);

  // Q projection: f32 A direct (fused cast in staging)
  gemm_f32a<1, 1><<<(unsigned)(MQ / 128 * 2), 256, 0, stream>>>(
      q_embeds, Wb, bq, nullptr, Qst, nullptr);

  // K+V projection: f32 ctx direct (fused cast in staging, no prepass)
  gemm_f32a<0, 2><<<(unsigned)(MKV / 128 * 4), 256, 0, stream>>>(
      ctx, Wb + 512 * 512, bk, bv, Kst, Vst);

  attn_kernel<<<NT * NB, 256, 0, stream>>>(Kst, Vst, Qst, mask, wout, attnst);

  gemm_o<<<(unsigned)(MQ / 128 * 4), 256, 0, stream>>>(attnst, Wb + 3 * 512 * 512, bo, out0);
}

// Round 17
// 734.500 us; speedup vs baseline: 1.2236x; 1.2236x over previous
//
#include <hip/hip_runtime.h>
#include <hip/hip_bf16.h>

typedef __attribute__((ext_vector_type(8))) short short8;
typedef __attribute__((ext_vector_type(4))) float f32x4;

#define NT 32
#define NB 64
#define NA 16
#define NF 128
#define DT 512
#define NH 8
#define NHD 64

// f32 -> bf16 RNE via compiler intrinsic (m240: compiler casts are fast AND correct;
// hand-written v_cvt_pk_bf16_f32 asm was r10's correctness bug)
__device__ __forceinline__ unsigned short f2b(float f) {
  return __bfloat16_as_ushort(__float2bfloat16(f));
}
__device__ __forceinline__ float b2f(unsigned short u) {
  union { unsigned u; float f; } c; c.u = ((unsigned)u) << 16;
  return c.f;
}
__device__ __forceinline__ unsigned cvt2(float a, float b) {
  return (unsigned)f2b(a) | ((unsigned)f2b(b) << 16);
}

__device__ __forceinline__ void gload16(const void* g, void* l) {
  __builtin_amdgcn_global_load_lds(
      (const __attribute__((address_space(1))) void*)g,
      (__attribute__((address_space(3))) void*)l, 16, 0, 0);
}

#define BAR() asm volatile("s_barrier" ::: "memory")

// ---------------- all 4 weight casts in one launch ----------------
__global__ __launch_bounds__(256) void cast4_kernel(const float* __restrict__ w0,
                                                    const float* __restrict__ w1,
                                                    const float* __restrict__ w2,
                                                    const float* __restrict__ w3,
                                                    unsigned short* __restrict__ dst) {
  const int mat = blockIdx.x >> 7;
  const float* src = (mat == 0) ? w0 : (mat == 1) ? w1 : (mat == 2) ? w2 : w3;
  long i = ((long)(blockIdx.x & 127) * 256 + threadIdx.x) * 8;
  float4 v0 = *(const float4*)(src + i);
  float4 v1 = *(const float4*)(src + i + 4);
  uint4 o;
  o.x = cvt2(v0.x, v0.y);
  o.y = cvt2(v0.z, v0.w);
  o.z = cvt2(v1.x, v1.y);
  o.w = cvt2(v1.z, v1.w);
  *(uint4*)(dst + (long)mat * 512 * 512 + i) = o;
}

// =============== 128x256 GEMM, f32 A staged raw into LDS (r13-proven, best) ===============
// 256 threads = 4 waves (2M x 2N), per-wave 64x128 out (acc 4x8). BK=32, 16 K-tiles,
// 2 LDS slots (64 KB -> 2 blocks/CU). Stage-at-top, counted vmcnt(8), 2 barriers/tile.
// Swizzles: A rows 128 B: 16B-chunk ^= (row&7); B rows 64 B: 16B-chunk ^= ((row>>1)&3).
// MODE 0 = KV (NCB=2: colTiles 0,1 -> K row-linear; 2,3 -> V row-permuted)
// MODE 1 = Q  (NCB=1: bf16 row-linear)
template <int MODE, int NCB>
__global__ __launch_bounds__(256, 2) void gemm_f32a(const float* __restrict__ A,
                                                    const unsigned short* __restrict__ Bg,
                                                    const float* __restrict__ bias0,
                                                    const float* __restrict__ bias1,
                                                    unsigned short* __restrict__ C0,
                                                    unsigned short* __restrict__ C1) {
  __shared__ __align__(16) float Asf[2][128 * 32];           // 16 KB / slot
  __shared__ __align__(16) unsigned short Bsb[2][256 * 32];  // 16 KB / slot
  const int tid = threadIdx.x;
  const int lane = tid & 63;
  const int l4 = lane & 15, lg = lane >> 4;
  const int w = tid >> 6;
  const int wm = w >> 1, wn = w & 1;

  const int nwg = gridDim.x;
  const int bid = blockIdx.x;
  const int swz = (bid & 7) * (nwg >> 3) + (bid >> 3);
  const long rowTile = swz >> NCB;
  const int colTile = swz & ((1 << NCB) - 1);

  const int sA = (lane & 7) ^ ((lane >> 3) & 7);
  const float* AglB = A + (rowTile * 128 + w * 32 + (lane >> 3)) * 512L + sA * 4;
  const int sB = (lane & 3) ^ ((lane >> 3) & 3);
  const unsigned short* BglB = Bg + ((long)colTile * 256 + w * 64 + (lane >> 2)) * 512L + sB * 8;

  auto stage = [&](int s, int kc) {
#pragma unroll
    for (int j = 0; j < 4; j++)
      gload16(AglB + j * (8 * 512L) + kc, &Asf[s][w * 1024 + j * 256]);
#pragma unroll
    for (int j = 0; j < 4; j++)
      gload16(BglB + j * (16 * 512L) + kc, &Bsb[s][w * 2048 + j * 512]);
  };

  const f32x4 zero = {0.f, 0.f, 0.f, 0.f};
  f32x4 acc[4][8];
#pragma unroll
  for (int i = 0; i < 4; i++)
#pragma unroll
    for (int j = 0; j < 8; j++) acc[i][j] = zero;

  const int chA = (l4 & 7);
  const int chB = ((l4 >> 1) & 3);

  stage(0, 0);

#pragma unroll 1
  for (int T = 0; T < 16; T++) {
    const int s = T & 1;
    BAR();
    if (T < 15) {
      stage(s ^ 1, (T + 1) * 32);
      asm volatile("s_waitcnt vmcnt(8)" ::: "memory");
    } else {
      asm volatile("s_waitcnt vmcnt(0)" ::: "memory");
    }
    BAR();
    short8 bf[8];
#pragma unroll
    for (int n = 0; n < 8; n++) {
      int rb = wn * 128 + n * 16 + l4;
      bf[n] = *(const short8*)&Bsb[s][rb * 32 + (lg ^ chB) * 8];
    }
    short8 af[4];
#pragma unroll
    for (int m = 0; m < 4; m++) {
      int ra = wm * 64 + m * 16 + l4;
      int c0 = (lg * 2) ^ chA;
      f32x4 p0 = *(const f32x4*)&Asf[s][ra * 32 + c0 * 4];
      f32x4 p1 = *(const f32x4*)&Asf[s][ra * 32 + (c0 ^ 1) * 4];
      union { unsigned u[4]; short8 s8; } cv;
      cv.u[0] = cvt2(p0[0], p0[1]);
      cv.u[1] = cvt2(p0[2], p0[3]);
      cv.u[2] = cvt2(p1[0], p1[1]);
      cv.u[3] = cvt2(p1[2], p1[3]);
      af[m] = cv.s8;
    }
    __builtin_amdgcn_s_setprio(1);
#pragma unroll
    for (int m = 0; m < 4; m++)
#pragma unroll
      for (int n = 0; n < 8; n++)
        acc[m][n] = __builtin_amdgcn_mfma_f32_16x16x32_bf16(af[m], bf[n], acc[m][n], 0, 0, 0);
    __builtin_amdgcn_s_setprio(0);
  }

  const long rowBase = rowTile * 128 + wm * 64;

  if constexpr (MODE == 0) {  // KV
    if (colTile < 2) {        // K: row-linear ((t,f,b) reshape is a memory no-op)
#pragma unroll
      for (int n = 0; n < 8; n++) {
        int gCol = colTile * 256 + wn * 128 + n * 16 + l4;
        float bs = bias0[gCol];
#pragma unroll
        for (int m = 0; m < 4; m++)
#pragma unroll
          for (int r = 0; r < 4; r++) {
            long gRow = rowBase + m * 16 + lg * 4 + r;
            C0[gRow * 512 + gCol] = f2b(acc[m][n][r] + bs);
          }
      }
    } else {  // V: row (fi*64+bi) -> (bi*128+fi) within each t
#pragma unroll
      for (int n = 0; n < 8; n++) {
        int gCol = (colTile - 2) * 256 + wn * 128 + n * 16 + l4;
        float bs = bias1[gCol];
#pragma unroll
        for (int m = 0; m < 4; m++)
#pragma unroll
          for (int r = 0; r < 4; r++) {
            long gRow = rowBase + m * 16 + lg * 4 + r;
            long rr = gRow & 8191;
            long vrow = (gRow - rr) + ((rr & 63) << 7) + (rr >> 6);
            C1[vrow * 512 + gCol] = f2b(acc[m][n][r] + bs);
          }
      }
    }
  } else {  // Q: bf16 row-linear
#pragma unroll
    for (int n = 0; n < 8; n++) {
      int gCol = colTile * 256 + wn * 128 + n * 16 + l4;
      float bs = bias0[gCol];
#pragma unroll
      for (int m = 0; m < 4; m++)
#pragma unroll
        for (int r = 0; r < 4; r++) {
          long gRow = rowBase + m * 16 + lg * 4 + r;
          C0[gRow * 512 + gCol] = f2b(acc[m][n][r] + bs);
        }
    }
  }
}

// ---------------- O projection (r7-proven): glds bf16 A/B, 128^2, f32 out ----------------
__global__ __launch_bounds__(256) void gemm_o(const unsigned short* __restrict__ A,
                                              const unsigned short* __restrict__ Bg,
                                              const float* __restrict__ bias0,
                                              float* __restrict__ C) {
  __shared__ __align__(16) unsigned short As[128 * 32];
  __shared__ __align__(16) unsigned short Bs[128 * 32];
  const int tid = threadIdx.x;
  const int lane = tid & 63;
  const int l4 = lane & 15, lg = lane >> 4;
  const int w = tid >> 6;
  const int wm = w >> 1, wn = w & 1;

  const int nwg = gridDim.x;
  const int bid = blockIdx.x;
  const int swz = (bid & 7) * (nwg >> 3) + (bid >> 3);
  const long rowTile = swz >> 2;
  const int colTile = swz & 3;

  const int srow = lane >> 2;
  const int scol = (lane & 3) * 8;
  const unsigned short* Ab = A + (rowTile * 128 + w * 16 + srow) * 512L + scol;
  const unsigned short* Ab2 = Ab + 64 * 512L;
  const unsigned short* Bb = Bg + ((long)colTile * 128 + w * 16 + srow) * 512L + scol;
  const unsigned short* Bb2 = Bb + 64 * 512L;
  unsigned short* lA = As + w * 512;
  unsigned short* lA2 = As + (w + 4) * 512;
  unsigned short* lB = Bs + w * 512;
  unsigned short* lB2 = Bs + (w + 4) * 512;

  const f32x4 zero = {0.f, 0.f, 0.f, 0.f};
  f32x4 acc[4][4];
#pragma unroll
  for (int i = 0; i < 4; i++)
#pragma unroll
    for (int j = 0; j < 4; j++) acc[i][j] = zero;

  for (int k0 = 0; k0 < 512; k0 += 32) {
    gload16(Ab + k0, lA);
    gload16(Ab2 + k0, lA2);
    gload16(Bb + k0, lB);
    gload16(Bb2 + k0, lB2);
    __syncthreads();
    short8 af[4], bfr[4];
#pragma unroll
    for (int i = 0; i < 4; i++)
      af[i] = *(const short8*)(As + (wm * 64 + i * 16 + l4) * 32 + lg * 8);
#pragma unroll
    for (int j = 0; j < 4; j++)
      bfr[j] = *(const short8*)(Bs + (wn * 64 + j * 16 + l4) * 32 + lg * 8);
#pragma unroll
    for (int i = 0; i < 4; i++)
#pragma unroll
      for (int j = 0; j < 4; j++)
        acc[i][j] = __builtin_amdgcn_mfma_f32_16x16x32_bf16(af[i], bfr[j], acc[i][j], 0, 0, 0);
    __syncthreads();
  }

  const long rowBase = rowTile * 128 + wm * 64;
#pragma unroll
  for (int j = 0; j < 4; j++) {
    int gCol = colTile * 128 + wn * 64 + j * 16 + l4;
    float bs = bias0[gCol];
#pragma unroll
    for (int i = 0; i < 4; i++)
#pragma unroll
      for (int r = 0; r < 4; r++) {
        long gRow = rowBase + i * 16 + lg * 4 + r;
        long tt = gRow >> 10;
        long bi = (gRow >> 4) & 63;
        long ai = gRow & 15;
        long orow = ((tt * 16 + ai) << 6) + bi;
        C[orow * 512 + gCol] = acc[i][j][r] + bs;
      }
  }
}

// ---------------- attention (r15-proven): slice-staged K and V, MFMA QK^T + PV ----------------
__global__ __launch_bounds__(256) void attn_kernel(const unsigned short* __restrict__ Kst,
                                                   const unsigned short* __restrict__ Vst,
                                                   const unsigned short* __restrict__ Qst,
                                                   const int* __restrict__ mask,
                                                   float* __restrict__ wout,
                                                   unsigned short* __restrict__ attn_out) {
  __shared__ __align__(16) unsigned short wt[4][16][136];  // per-wave W^T bf16 [a][f]
  __shared__ __align__(16) unsigned short Vl[4][2][2048];  // per-wave slice bufs, 2 x 4KB
  __shared__ int msh[NF];
  const int tid = threadIdx.x;
  const int lane = tid & 63;
  const int l4 = lane & 15, lg = lane >> 4;
  const int w = tid >> 6;
  const int tb = blockIdx.x;
  const int b = tb & 63;
  if (tid < NF) msh[tid] = mask[b * NF + tid];
  __syncthreads();

  const unsigned short* Kbase = Kst + (long)tb * NF * DT;
  const unsigned short* Vbase = Vst + (long)tb * NF * DT;
  const unsigned short* Qbase = Qst + (long)tb * NA * DT;
  const f32x4 zero = {0.f, 0.f, 0.f, 0.f};

  const int vsr = lane >> 3;
  const int vsc = lane & 7;

  for (int hh = 0; hh < 2; hh++) {
    const int h = w * 2 + hh;
    const int co = h * 64;

    auto stageS = [&](const unsigned short* base, int buf, int sl) {
#pragma unroll
      for (int i = 0; i < 4; i++) {
        const unsigned short* src =
            base + (long)(sl * 32 + i * 8 + vsr) * DT + co + ((vsc ^ i) * 8);
        gload16(src, &Vl[w][buf][i * 512]);
      }
    };

    short8 qf0 = *(const short8*)(Qbase + (long)l4 * DT + co + lg * 8);
    short8 qf1 = *(const short8*)(Qbase + (long)l4 * DT + co + 32 + lg * 8);
    stageS(Kbase, 0, 0);
    stageS(Kbase, 1, 1);

    f32x4 acc[8];
#pragma unroll
    for (int i = 0; i < 8; i++) acc[i] = zero;
#pragma unroll
    for (int mh = 0; mh < 4; mh++) {
      const int buf = mh & 1;
      asm volatile("s_waitcnt vmcnt(4)" ::: "memory");
#pragma unroll
      for (int mm = 0; mm < 2; mm++) {
        const int m0 = mh * 2 + mm;
        const int r = mm * 16 + l4;
        short8 kf0 = *(const short8*)&Vl[w][buf][r * 64 + ((lg ^ (r >> 3)) * 8)];
        short8 kf1 = *(const short8*)&Vl[w][buf][r * 64 + (((4 + lg) ^ (r >> 3)) * 8)];
        acc[m0] = __builtin_amdgcn_mfma_f32_16x16x32_bf16(kf0, qf0, acc[m0], 0, 0, 0);
        acc[m0] = __builtin_amdgcn_mfma_f32_16x16x32_bf16(kf1, qf1, acc[m0], 0, 0, 0);
      }
      asm volatile("s_waitcnt lgkmcnt(0)" ::: "memory");
      __builtin_amdgcn_sched_barrier(0);
      if (mh < 2) stageS(Kbase, buf, mh + 2);
      else stageS(Vbase, buf, mh - 2);
    }

    float lv[8][4];
    float mx = -3.0e38f;
#pragma unroll
    for (int m0 = 0; m0 < 8; m0++)
#pragma unroll
      for (int r = 0; r < 4; r++) {
        int f = m0 * 16 + lg * 4 + r;
        float v = acc[m0][r] * 0.125f;
        if (msh[f] == 0) v = -1.0e9f;
        lv[m0][r] = v;
        mx = fmaxf(mx, v);
      }
    mx = fmaxf(mx, __shfl_xor(mx, 16, 64));
    mx = fmaxf(mx, __shfl_xor(mx, 32, 64));
    float s = 0.f;
#pragma unroll
    for (int m0 = 0; m0 < 8; m0++)
#pragma unroll
      for (int r = 0; r < 4; r++) {
        float p = __expf(lv[m0][r] - mx);
        lv[m0][r] = p;
        s += p;
      }
    s += __shfl_xor(s, 16, 64);
    s += __shfl_xor(s, 32, 64);
    float inv = 1.0f / s;
    float* wrow = wout + ((long)tb * NH + h) * (NF * NA);
#pragma unroll
    for (int m0 = 0; m0 < 8; m0++)
#pragma unroll
      for (int r = 0; r < 4; r++) {
        int f = m0 * 16 + lg * 4 + r;
        float wv = lv[m0][r] * inv;
        wrow[f * 16 + l4] = wv;
        wt[w][l4][f] = f2b(wv);
      }
    asm volatile("s_waitcnt lgkmcnt(0)" ::: "memory");
    __builtin_amdgcn_sched_barrier(0);

    f32x4 pacc[4];
#pragma unroll
    for (int m0 = 0; m0 < 4; m0++) pacc[m0] = zero;
#pragma unroll 1
    for (int ks = 0; ks < 4; ks++) {
      const int buf = ks & 1;
      if (ks < 3)
        asm volatile("s_waitcnt vmcnt(4)" ::: "memory");
      else
        asm volatile("s_waitcnt vmcnt(0)" ::: "memory");
      short8 wf = *(const short8*)&wt[w][l4][ks * 32 + lg * 8];
#pragma unroll
      for (int m0 = 0; m0 < 4; m0++) {
        const int hdl = m0 * 16 + l4;
        const int ch = ((hdl >> 3) ^ lg) & 7;
        const int cb = ch * 8 + (hdl & 7);
        short8 vf;
#pragma unroll
        for (int j = 0; j < 8; j++)
          vf[j] = (short)Vl[w][buf][(lg * 8 + j) * 64 + cb];
        pacc[m0] = __builtin_amdgcn_mfma_f32_16x16x32_bf16(vf, wf, pacc[m0], 0, 0, 0);
      }
      if (ks < 2) {
        asm volatile("s_waitcnt lgkmcnt(0)" ::: "memory");
        __builtin_amdgcn_sched_barrier(0);
        stageS(Vbase, buf, ks + 2);
      }
    }
#pragma unroll
    for (int m0 = 0; m0 < 4; m0++)
#pragma unroll
      for (int r = 0; r < 4; r++)
        attn_out[((long)tb * NA + l4) * DT + co + m0 * 16 + lg * 4 + r] = f2b(pacc[m0][r]);
  }
}

extern "C" void kernel_launch(void* const* d_in, const int* in_sizes, int n_in,
                              void* d_out, int out_size, void* d_ws, size_t ws_size,
                              hipStream_t stream) {
  const float* q_embeds = (const float*)d_in[0];
  const float* ctx = (const float*)d_in[1];
  const int* mask = (const int*)d_in[2];
  const float* Wq = (const float*)d_in[3];
  const float* bq = (const float*)d_in[4];
  const float* Wk = (const float*)d_in[5];
  const float* bk = (const float*)d_in[6];
  const float* Wv = (const float*)d_in[7];
  const float* bv = (const float*)d_in[8];
  const float* Wo = (const float*)d_in[9];
  const float* bo = (const float*)d_in[10];

  float* out0 = (float*)d_out;                   // (t,a,b,d) f32
  float* wout = out0 + (long)NT * NA * NB * DT;  // (t,b,H,f,a) f32

  const long W_ELEMS = 4L * 512 * 512;
  const long MQ = (long)NT * NB * NA;    // 32768
  const long MKV = (long)NT * NF * NB;   // 262144
  unsigned short* Wb = (unsigned short*)d_ws;
  unsigned short* Qst = Wb + W_ELEMS;
  unsigned short* Kst = Qst + MQ * DT;
  unsigned short* Vst = Kst + MKV * DT;
  unsigned short* attnst = Vst + MKV * DT;
  size_t needed = (size_t)(W_ELEMS + 2 * MQ * DT + 2 * MKV * DT) * 2;
  if (ws_size < needed) return;

  cast4_kernel<<<512, 256, 0, stream>>>(Wq, Wk, Wv, Wo, Wb);

  // Q projection: f32 A direct (fused cast in staging)
  gemm_f32a<1, 1><<<(unsigned)(MQ / 128 * 2), 256, 0, stream>>>(
      q_embeds, Wb, bq, nullptr, Qst, nullptr);

  // K+V projection: f32 ctx direct (fused cast in staging, no prepass)
  gemm_f32a<0, 2><<<(unsigned)(MKV / 128 * 4), 256, 0, stream>>>(
      ctx, Wb + 512 * 512, bk, bv, Kst, Vst);

  attn_kernel<<<NT * NB, 256, 0, stream>>>(Kst, Vst, Qst, mask, wout, attnst);

  gemm_o<<<(unsigned)(MQ / 128 * 4), 256, 0, stream>>>(attnst, Wb + 3 * 512 * 512, bo, out0);
}

// Round 18
// 725.745 us; speedup vs baseline: 1.2383x; 1.0121x over previous
//
#include <hip/hip_runtime.h>
#include <hip/hip_bf16.h>

typedef __attribute__((ext_vector_type(8))) short short8;
typedef __attribute__((ext_vector_type(4))) float f32x4;

#define NT 32
#define NB 64
#define NA 16
#define NF 128
#define DT 512
#define NH 8
#define NHD 64

// f32 -> bf16 RNE via compiler intrinsic (m240: compiler casts are fast AND correct;
// hand-written v_cvt_pk_bf16_f32 asm was r10's correctness bug)
__device__ __forceinline__ unsigned short f2b(float f) {
  return __bfloat16_as_ushort(__float2bfloat16(f));
}
__device__ __forceinline__ float b2f(unsigned short u) {
  union { unsigned u; float f; } c; c.u = ((unsigned)u) << 16;
  return c.f;
}
__device__ __forceinline__ unsigned cvt2(float a, float b) {
  return (unsigned)f2b(a) | ((unsigned)f2b(b) << 16);
}

__device__ __forceinline__ void gload16(const void* g, void* l) {
  __builtin_amdgcn_global_load_lds(
      (const __attribute__((address_space(1))) void*)g,
      (__attribute__((address_space(3))) void*)l, 16, 0, 0);
}

#define BAR() asm volatile("s_barrier" ::: "memory")

// ---------------- all 4 weight casts in one launch ----------------
__global__ __launch_bounds__(256) void cast4_kernel(const float* __restrict__ w0,
                                                    const float* __restrict__ w1,
                                                    const float* __restrict__ w2,
                                                    const float* __restrict__ w3,
                                                    unsigned short* __restrict__ dst) {
  const int mat = blockIdx.x >> 7;
  const float* src = (mat == 0) ? w0 : (mat == 1) ? w1 : (mat == 2) ? w2 : w3;
  long i = ((long)(blockIdx.x & 127) * 256 + threadIdx.x) * 8;
  float4 v0 = *(const float4*)(src + i);
  float4 v1 = *(const float4*)(src + i + 4);
  uint4 o;
  o.x = cvt2(v0.x, v0.y);
  o.y = cvt2(v0.z, v0.w);
  o.z = cvt2(v1.x, v1.y);
  o.w = cvt2(v1.z, v1.w);
  *(uint4*)(dst + (long)mat * 512 * 512 + i) = o;
}

// =============== FUSED Q+KV projection: 128x256 GEMM, f32 A staged raw into LDS ===============
// r13/r17-proven skeleton, unchanged K-loop. Single dispatch: blocks [0,8192) = KV
// (ctx A, Wk|Wv B, K/V epilogues), blocks [8192,8704) = Q (q_embeds A, Wq B, Qst
// epilogue). Q appended last so its blocks back-fill KV's retire slots (KV kernel is
// latency-bound with idle issue capacity). Per-segment XCD-bijective swizzle.
// 256 threads = 4 waves (2M x 2N), per-wave 64x128 out (acc 4x8). BK=32, 16 K-tiles,
// 2 LDS slots (64 KB -> 2 blocks/CU). Stage-at-top, counted vmcnt(8), 2 barriers/tile.
// Swizzles: A rows 128 B: 16B-chunk ^= (row&7); B rows 64 B: 16B-chunk ^= ((row>>1)&3).
__global__ __launch_bounds__(256, 2) void gemm_fused(const float* __restrict__ Aq,
                                                     const float* __restrict__ Akv,
                                                     const unsigned short* __restrict__ Wb,
                                                     const float* __restrict__ bq,
                                                     const float* __restrict__ bk,
                                                     const float* __restrict__ bv,
                                                     unsigned short* __restrict__ Qst,
                                                     unsigned short* __restrict__ Kst,
                                                     unsigned short* __restrict__ Vst) {
  __shared__ __align__(16) float Asf[2][128 * 32];           // 16 KB / slot
  __shared__ __align__(16) unsigned short Bsb[2][256 * 32];  // 16 KB / slot
  const int tid = threadIdx.x;
  const int lane = tid & 63;
  const int l4 = lane & 15, lg = lane >> 4;
  const int w = tid >> 6;
  const int wm = w >> 1, wn = w & 1;

  const int bid = blockIdx.x;
  const bool isQ = bid >= 8192;
  const int lb = isQ ? (bid - 8192) : bid;
  const int nwgl = isQ ? 512 : 8192;
  const int swz = (lb & 7) * (nwgl >> 3) + (lb >> 3);
  const int ncb = isQ ? 1 : 2;
  const long rowTile = swz >> ncb;
  const int colTile = swz & ((1 << ncb) - 1);

  const float* A = isQ ? Aq : Akv;
  const unsigned short* Bg = isQ ? Wb : (Wb + 512 * 512);

  const int sA = (lane & 7) ^ ((lane >> 3) & 7);
  const float* AglB = A + (rowTile * 128 + w * 32 + (lane >> 3)) * 512L + sA * 4;
  const int sB = (lane & 3) ^ ((lane >> 3) & 3);
  const unsigned short* BglB = Bg + ((long)colTile * 256 + w * 64 + (lane >> 2)) * 512L + sB * 8;

  auto stage = [&](int s, int kc) {
#pragma unroll
    for (int j = 0; j < 4; j++)
      gload16(AglB + j * (8 * 512L) + kc, &Asf[s][w * 1024 + j * 256]);
#pragma unroll
    for (int j = 0; j < 4; j++)
      gload16(BglB + j * (16 * 512L) + kc, &Bsb[s][w * 2048 + j * 512]);
  };

  const f32x4 zero = {0.f, 0.f, 0.f, 0.f};
  f32x4 acc[4][8];
#pragma unroll
  for (int i = 0; i < 4; i++)
#pragma unroll
    for (int j = 0; j < 8; j++) acc[i][j] = zero;

  const int chA = (l4 & 7);
  const int chB = ((l4 >> 1) & 3);

  stage(0, 0);

#pragma unroll 1
  for (int T = 0; T < 16; T++) {
    const int s = T & 1;
    BAR();
    if (T < 15) {
      stage(s ^ 1, (T + 1) * 32);
      asm volatile("s_waitcnt vmcnt(8)" ::: "memory");
    } else {
      asm volatile("s_waitcnt vmcnt(0)" ::: "memory");
    }
    BAR();
    short8 bf[8];
#pragma unroll
    for (int n = 0; n < 8; n++) {
      int rb = wn * 128 + n * 16 + l4;
      bf[n] = *(const short8*)&Bsb[s][rb * 32 + (lg ^ chB) * 8];
    }
    short8 af[4];
#pragma unroll
    for (int m = 0; m < 4; m++) {
      int ra = wm * 64 + m * 16 + l4;
      int c0 = (lg * 2) ^ chA;
      f32x4 p0 = *(const f32x4*)&Asf[s][ra * 32 + c0 * 4];
      f32x4 p1 = *(const f32x4*)&Asf[s][ra * 32 + (c0 ^ 1) * 4];
      union { unsigned u[4]; short8 s8; } cv;
      cv.u[0] = cvt2(p0[0], p0[1]);
      cv.u[1] = cvt2(p0[2], p0[3]);
      cv.u[2] = cvt2(p1[0], p1[1]);
      cv.u[3] = cvt2(p1[2], p1[3]);
      af[m] = cv.s8;
    }
    __builtin_amdgcn_s_setprio(1);
#pragma unroll
    for (int m = 0; m < 4; m++)
#pragma unroll
      for (int n = 0; n < 8; n++)
        acc[m][n] = __builtin_amdgcn_mfma_f32_16x16x32_bf16(af[m], bf[n], acc[m][n], 0, 0, 0);
    __builtin_amdgcn_s_setprio(0);
  }

  const long rowBase = rowTile * 128 + wm * 64;

  if (isQ) {  // Q: bf16 row-linear
#pragma unroll
    for (int n = 0; n < 8; n++) {
      int gCol = colTile * 256 + wn * 128 + n * 16 + l4;
      float bs = bq[gCol];
#pragma unroll
      for (int m = 0; m < 4; m++)
#pragma unroll
        for (int r = 0; r < 4; r++) {
          long gRow = rowBase + m * 16 + lg * 4 + r;
          Qst[gRow * 512 + gCol] = f2b(acc[m][n][r] + bs);
        }
    }
  } else if (colTile < 2) {  // K: row-linear ((t,f,b) reshape is a memory no-op)
#pragma unroll
    for (int n = 0; n < 8; n++) {
      int gCol = colTile * 256 + wn * 128 + n * 16 + l4;
      float bs = bk[gCol];
#pragma unroll
      for (int m = 0; m < 4; m++)
#pragma unroll
        for (int r = 0; r < 4; r++) {
          long gRow = rowBase + m * 16 + lg * 4 + r;
          Kst[gRow * 512 + gCol] = f2b(acc[m][n][r] + bs);
        }
    }
  } else {  // V: row (fi*64+bi) -> (bi*128+fi) within each t
#pragma unroll
    for (int n = 0; n < 8; n++) {
      int gCol = (colTile - 2) * 256 + wn * 128 + n * 16 + l4;
      float bs = bv[gCol];
#pragma unroll
      for (int m = 0; m < 4; m++)
#pragma unroll
        for (int r = 0; r < 4; r++) {
          long gRow = rowBase + m * 16 + lg * 4 + r;
          long rr = gRow & 8191;
          long vrow = (gRow - rr) + ((rr & 63) << 7) + (rr >> 6);
          Vst[vrow * 512 + gCol] = f2b(acc[m][n][r] + bs);
        }
    }
  }
}

// ---------------- O projection (r7-proven): glds bf16 A/B, 128^2, f32 out ----------------
__global__ __launch_bounds__(256) void gemm_o(const unsigned short* __restrict__ A,
                                              const unsigned short* __restrict__ Bg,
                                              const float* __restrict__ bias0,
                                              float* __restrict__ C) {
  __shared__ __align__(16) unsigned short As[128 * 32];
  __shared__ __align__(16) unsigned short Bs[128 * 32];
  const int tid = threadIdx.x;
  const int lane = tid & 63;
  const int l4 = lane & 15, lg = lane >> 4;
  const int w = tid >> 6;
  const int wm = w >> 1, wn = w & 1;

  const int nwg = gridDim.x;
  const int bid = blockIdx.x;
  const int swz = (bid & 7) * (nwg >> 3) + (bid >> 3);
  const long rowTile = swz >> 2;
  const int colTile = swz & 3;

  const int srow = lane >> 2;
  const int scol = (lane & 3) * 8;
  const unsigned short* Ab = A + (rowTile * 128 + w * 16 + srow) * 512L + scol;
  const unsigned short* Ab2 = Ab + 64 * 512L;
  const unsigned short* Bb = Bg + ((long)colTile * 128 + w * 16 + srow) * 512L + scol;
  const unsigned short* Bb2 = Bb + 64 * 512L;
  unsigned short* lA = As + w * 512;
  unsigned short* lA2 = As + (w + 4) * 512;
  unsigned short* lB = Bs + w * 512;
  unsigned short* lB2 = Bs + (w + 4) * 512;

  const f32x4 zero = {0.f, 0.f, 0.f, 0.f};
  f32x4 acc[4][4];
#pragma unroll
  for (int i = 0; i < 4; i++)
#pragma unroll
    for (int j = 0; j < 4; j++) acc[i][j] = zero;

  for (int k0 = 0; k0 < 512; k0 += 32) {
    gload16(Ab + k0, lA);
    gload16(Ab2 + k0, lA2);
    gload16(Bb + k0, lB);
    gload16(Bb2 + k0, lB2);
    __syncthreads();
    short8 af[4], bfr[4];
#pragma unroll
    for (int i = 0; i < 4; i++)
      af[i] = *(const short8*)(As + (wm * 64 + i * 16 + l4) * 32 + lg * 8);
#pragma unroll
    for (int j = 0; j < 4; j++)
      bfr[j] = *(const short8*)(Bs + (wn * 64 + j * 16 + l4) * 32 + lg * 8);
#pragma unroll
    for (int i = 0; i < 4; i++)
#pragma unroll
      for (int j = 0; j < 4; j++)
        acc[i][j] = __builtin_amdgcn_mfma_f32_16x16x32_bf16(af[i], bfr[j], acc[i][j], 0, 0, 0);
    __syncthreads();
  }

  const long rowBase = rowTile * 128 + wm * 64;
#pragma unroll
  for (int j = 0; j < 4; j++) {
    int gCol = colTile * 128 + wn * 64 + j * 16 + l4;
    float bs = bias0[gCol];
#pragma unroll
    for (int i = 0; i < 4; i++)
#pragma unroll
      for (int r = 0; r < 4; r++) {
        long gRow = rowBase + i * 16 + lg * 4 + r;
        long tt = gRow >> 10;
        long bi = (gRow >> 4) & 63;
        long ai = gRow & 15;
        long orow = ((tt * 16 + ai) << 6) + bi;
        C[orow * 512 + gCol] = acc[i][j][r] + bs;
      }
  }
}

// ---------------- attention (r15-proven): slice-staged K and V, MFMA QK^T + PV ----------------
__global__ __launch_bounds__(256) void attn_kernel(const unsigned short* __restrict__ Kst,
                                                   const unsigned short* __restrict__ Vst,
                                                   const unsigned short* __restrict__ Qst,
                                                   const int* __restrict__ mask,
                                                   float* __restrict__ wout,
                                                   unsigned short* __restrict__ attn_out) {
  __shared__ __align__(16) unsigned short wt[4][16][136];  // per-wave W^T bf16 [a][f]
  __shared__ __align__(16) unsigned short Vl[4][2][2048];  // per-wave slice bufs, 2 x 4KB
  __shared__ int msh[NF];
  const int tid = threadIdx.x;
  const int lane = tid & 63;
  const int l4 = lane & 15, lg = lane >> 4;
  const int w = tid >> 6;
  const int tb = blockIdx.x;
  const int b = tb & 63;
  if (tid < NF) msh[tid] = mask[b * NF + tid];
  __syncthreads();

  const unsigned short* Kbase = Kst + (long)tb * NF * DT;
  const unsigned short* Vbase = Vst + (long)tb * NF * DT;
  const unsigned short* Qbase = Qst + (long)tb * NA * DT;
  const f32x4 zero = {0.f, 0.f, 0.f, 0.f};

  const int vsr = lane >> 3;
  const int vsc = lane & 7;

  for (int hh = 0; hh < 2; hh++) {
    const int h = w * 2 + hh;
    const int co = h * 64;

    auto stageS = [&](const unsigned short* base, int buf, int sl) {
#pragma unroll
      for (int i = 0; i < 4; i++) {
        const unsigned short* src =
            base + (long)(sl * 32 + i * 8 + vsr) * DT + co + ((vsc ^ i) * 8);
        gload16(src, &Vl[w][buf][i * 512]);
      }
    };

    short8 qf0 = *(const short8*)(Qbase + (long)l4 * DT + co + lg * 8);
    short8 qf1 = *(const short8*)(Qbase + (long)l4 * DT + co + 32 + lg * 8);
    stageS(Kbase, 0, 0);
    stageS(Kbase, 1, 1);

    f32x4 acc[8];
#pragma unroll
    for (int i = 0; i < 8; i++) acc[i] = zero;
#pragma unroll
    for (int mh = 0; mh < 4; mh++) {
      const int buf = mh & 1;
      asm volatile("s_waitcnt vmcnt(4)" ::: "memory");
#pragma unroll
      for (int mm = 0; mm < 2; mm++) {
        const int m0 = mh * 2 + mm;
        const int r = mm * 16 + l4;
        short8 kf0 = *(const short8*)&Vl[w][buf][r * 64 + ((lg ^ (r >> 3)) * 8)];
        short8 kf1 = *(const short8*)&Vl[w][buf][r * 64 + (((4 + lg) ^ (r >> 3)) * 8)];
        acc[m0] = __builtin_amdgcn_mfma_f32_16x16x32_bf16(kf0, qf0, acc[m0], 0, 0, 0);
        acc[m0] = __builtin_amdgcn_mfma_f32_16x16x32_bf16(kf1, qf1, acc[m0], 0, 0, 0);
      }
      asm volatile("s_waitcnt lgkmcnt(0)" ::: "memory");
      __builtin_amdgcn_sched_barrier(0);
      if (mh < 2) stageS(Kbase, buf, mh + 2);
      else stageS(Vbase, buf, mh - 2);
    }

    float lv[8][4];
    float mx = -3.0e38f;
#pragma unroll
    for (int m0 = 0; m0 < 8; m0++)
#pragma unroll
      for (int r = 0; r < 4; r++) {
        int f = m0 * 16 + lg * 4 + r;
        float v = acc[m0][r] * 0.125f;
        if (msh[f] == 0) v = -1.0e9f;
        lv[m0][r] = v;
        mx = fmaxf(mx, v);
      }
    mx = fmaxf(mx, __shfl_xor(mx, 16, 64));
    mx = fmaxf(mx, __shfl_xor(mx, 32, 64));
    float s = 0.f;
#pragma unroll
    for (int m0 = 0; m0 < 8; m0++)
#pragma unroll
      for (int r = 0; r < 4; r++) {
        float p = __expf(lv[m0][r] - mx);
        lv[m0][r] = p;
        s += p;
      }
    s += __shfl_xor(s, 16, 64);
    s += __shfl_xor(s, 32, 64);
    float inv = 1.0f / s;
    float* wrow = wout + ((long)tb * NH + h) * (NF * NA);
#pragma unroll
    for (int m0 = 0; m0 < 8; m0++)
#pragma unroll
      for (int r = 0; r < 4; r++) {
        int f = m0 * 16 + lg * 4 + r;
        float wv = lv[m0][r] * inv;
        wrow[f * 16 + l4] = wv;
        wt[w][l4][f] = f2b(wv);
      }
    asm volatile("s_waitcnt lgkmcnt(0)" ::: "memory");
    __builtin_amdgcn_sched_barrier(0);

    f32x4 pacc[4];
#pragma unroll
    for (int m0 = 0; m0 < 4; m0++) pacc[m0] = zero;
#pragma unroll 1
    for (int ks = 0; ks < 4; ks++) {
      const int buf = ks & 1;
      if (ks < 3)
        asm volatile("s_waitcnt vmcnt(4)" ::: "memory");
      else
        asm volatile("s_waitcnt vmcnt(0)" ::: "memory");
      short8 wf = *(const short8*)&wt[w][l4][ks * 32 + lg * 8];
#pragma unroll
      for (int m0 = 0; m0 < 4; m0++) {
        const int hdl = m0 * 16 + l4;
        const int ch = ((hdl >> 3) ^ lg) & 7;
        const int cb = ch * 8 + (hdl & 7);
        short8 vf;
#pragma unroll
        for (int j = 0; j < 8; j++)
          vf[j] = (short)Vl[w][buf][(lg * 8 + j) * 64 + cb];
        pacc[m0] = __builtin_amdgcn_mfma_f32_16x16x32_bf16(vf, wf, pacc[m0], 0, 0, 0);
      }
      if (ks < 2) {
        asm volatile("s_waitcnt lgkmcnt(0)" ::: "memory");
        __builtin_amdgcn_sched_barrier(0);
        stageS(Vbase, buf, ks + 2);
      }
    }
#pragma unroll
    for (int m0 = 0; m0 < 4; m0++)
#pragma unroll
      for (int r = 0; r < 4; r++)
        attn_out[((long)tb * NA + l4) * DT + co + m0 * 16 + lg * 4 + r] = f2b(pacc[m0][r]);
  }
}

extern "C" void kernel_launch(void* const* d_in, const int* in_sizes, int n_in,
                              void* d_out, int out_size, void* d_ws, size_t ws_size,
                              hipStream_t stream) {
  const float* q_embeds = (const float*)d_in[0];
  const float* ctx = (const float*)d_in[1];
  const int* mask = (const int*)d_in[2];
  const float* Wq = (const float*)d_in[3];
  const float* bq = (const float*)d_in[4];
  const float* Wk = (const float*)d_in[5];
  const float* bk = (const float*)d_in[6];
  const float* Wv = (const float*)d_in[7];
  const float* bv = (const float*)d_in[8];
  const float* Wo = (const float*)d_in[9];
  const float* bo = (const float*)d_in[10];

  float* out0 = (float*)d_out;                   // (t,a,b,d) f32
  float* wout = out0 + (long)NT * NA * NB * DT;  // (t,b,H,f,a) f32

  const long W_ELEMS = 4L * 512 * 512;
  const long MQ = (long)NT * NB * NA;    // 32768
  const long MKV = (long)NT * NF * NB;   // 262144
  unsigned short* Wb = (unsigned short*)d_ws;
  unsigned short* Qst = Wb + W_ELEMS;
  unsigned short* Kst = Qst + MQ * DT;
  unsigned short* Vst = Kst + MKV * DT;
  unsigned short* attnst = Vst + MKV * DT;
  size_t needed = (size_t)(W_ELEMS + 2 * MQ * DT + 2 * MKV * DT) * 2;
  if (ws_size < needed) return;

  cast4_kernel<<<512, 256, 0, stream>>>(Wq, Wk, Wv, Wo, Wb);

  // Fused Q + KV projection: 8192 KV blocks then 512 Q blocks (Q back-fills KV tail)
  gemm_fused<<<8704, 256, 0, stream>>>(q_embeds, ctx, Wb, bq, bk, bv, Qst, Kst, Vst);

  attn_kernel<<<NT * NB, 256, 0, stream>>>(Kst, Vst, Qst, mask, wout, attnst);

  gemm_o<<<(unsigned)(MQ / 128 * 4), 256, 0, stream>>>(attnst, Wb + 3 * 512 * 512, bo, out0);
}